// Round 5
// baseline (172.080 us; speedup 1.0000x reference)
//
#include <hip/hip_runtime.h>
#include <hip/hip_bf16.h>
#include <stdint.h>

// out[i][j] = dot(x[i], y[j]) / max(|x[i]|*|y[j]|, 1e-8) / 0.05
// x,y: [4096,1024] f32; out: [4096,4096] f32
#define MDIM 4096
#define NDIM 4096
#define KDIM 1024
#define TEMP_INV 20.0f

#define BM 256
#define BN 128
#define BK 64
#define NT (KDIM / BK)       // 16 K-tiles
#define ABUF_E (BM * BK)     // 16384 elems = 32 KB per A buffer; 2 buffers = 64 KB total LDS

typedef __bf16 bf16x8 __attribute__((ext_vector_type(8)));
typedef float f32x16 __attribute__((ext_vector_type(16)));

typedef __attribute__((address_space(3))) void lds_void_t;
typedef __attribute__((address_space(1))) void glb_void_t;

__device__ __forceinline__ void async_copy16(const void* g, void* l) {
    __builtin_amdgcn_global_load_lds((glb_void_t*)(uintptr_t)g,
                                     (lds_void_t*)(uint32_t)(uintptr_t)l,
                                     16, 0, 0);
}

__device__ __forceinline__ unsigned short f32_to_bf16_rne(float f) {
    union { float f; uint32_t u; } v;
    v.f = f;
    uint32_t u = v.u;
    return (unsigned short)((u + 0x7FFFu + ((u >> 16) & 1u)) >> 16);
}

// Wave-per-row prep: no LDS, no __syncthreads. Block = 4 waves = 4 rows.
__global__ __launch_bounds__(256) void prep_kernel(const float* __restrict__ x,
                                                   const float* __restrict__ y,
                                                   unsigned short* __restrict__ xb,
                                                   unsigned short* __restrict__ yb,
                                                   float* __restrict__ rnx,
                                                   float* __restrict__ rny) {
    const int wv = threadIdx.x >> 6;
    const int lane = threadIdx.x & 63;
    const int row = blockIdx.x * 4 + wv;
    const float* src = blockIdx.y ? y : x;
    unsigned short* dst = blockIdx.y ? yb : xb;
    float* rn = blockIdx.y ? rny : rnx;

    const float4* s4 = (const float4*)(src + (size_t)row * KDIM);
    ushort4* d4 = (ushort4*)(dst + (size_t)row * KDIM);

    float ss = 0.0f;
#pragma unroll
    for (int it = 0; it < 4; ++it) {
        float4 v = s4[lane + it * 64];
        ss += v.x * v.x + v.y * v.y + v.z * v.z + v.w * v.w;
        ushort4 b;
        b.x = f32_to_bf16_rne(v.x);
        b.y = f32_to_bf16_rne(v.y);
        b.z = f32_to_bf16_rne(v.z);
        b.w = f32_to_bf16_rne(v.w);
        d4[lane + it * 64] = b;
    }
#pragma unroll
    for (int off = 32; off > 0; off >>= 1) ss += __shfl_down(ss, off);
    if (lane == 0) rn[row] = 1.0f / fmaxf(sqrtf(ss), 1e-8f);
}

// One K-tile. B comes GLOBAL -> REGISTER (no LDS): lane n32 reads row
// (colbase + n32), k-chunk (2s+half) — bit-identical to what the swizzled LDS
// path delivered (XOR cancels), each wave's per-tile B footprint = 64 rows x
// 128 B = one L2 line per row, L1-resident across the 4 k-slices. A stays in
// LDS (reused by 2 waves... 4 col-waves) with the verified chunk-XOR swizzle.
// One __syncthreads per tile: A-stage targets the other buffer (WAR-safe by
// the previous tile's barrier), vmcnt(0) drain at the barrier is ~free (loads
// are a full tile old).
template <bool STAGE>
__device__ __forceinline__ void ktile(const __bf16* __restrict__ buf,
                                      __bf16* __restrict__ nbuf,
                                      const unsigned short* gAsrc, int ktS,
                                      const unsigned short* gB0,
                                      const unsigned short* gB1, int ktB,
                                      int aB0, int aB1,
                                      int half, int rsw, int tid,
                                      f32x16& acc00, f32x16& acc01,
                                      f32x16& acc10, f32x16& acc11) {
    // B gathers first (longest latency, on the critical path of the first MFMA).
    bf16x8 b0[4], b1[4];
#pragma unroll
    for (int s = 0; s < 4; ++s) {
        const int ch = (2 * s + half) * 8;
        b0[s] = *(const bf16x8*)(gB0 + ktB + ch);
        b1[s] = *(const bf16x8*)(gB1 + ktB + ch);
    }
    // Stage next A tile into the other buffer (4 x 16B per thread).
    if constexpr (STAGE) {
#pragma unroll
        for (int seg = 0; seg < 4; ++seg)
            async_copy16(gAsrc + ktS + (size_t)(seg * 64) * KDIM, nbuf + seg * 4096 + tid * 8);
    }

    bf16x8 a[4];
#pragma unroll
    for (int s = 0; s < 4; ++s)
        a[s] = *(const bf16x8*)(buf + aB0 + ((2 * s + half) ^ rsw) * 8);
    __builtin_amdgcn_s_setprio(1);
#pragma unroll
    for (int s = 0; s < 4; ++s)
        acc00 = __builtin_amdgcn_mfma_f32_32x32x16_bf16(a[s], b0[s], acc00, 0, 0, 0);
#pragma unroll
    for (int s = 0; s < 4; ++s)
        acc01 = __builtin_amdgcn_mfma_f32_32x32x16_bf16(a[s], b1[s], acc01, 0, 0, 0);
    __builtin_amdgcn_s_setprio(0);

#pragma unroll
    for (int s = 0; s < 4; ++s)
        a[s] = *(const bf16x8*)(buf + aB1 + ((2 * s + half) ^ rsw) * 8);
    __builtin_amdgcn_s_setprio(1);
#pragma unroll
    for (int s = 0; s < 4; ++s)
        acc10 = __builtin_amdgcn_mfma_f32_32x32x16_bf16(a[s], b0[s], acc10, 0, 0, 0);
#pragma unroll
    for (int s = 0; s < 4; ++s)
        acc11 = __builtin_amdgcn_mfma_f32_32x32x16_bf16(a[s], b1[s], acc11, 0, 0, 0);
    __builtin_amdgcn_s_setprio(0);

    __syncthreads();
}

// 256x128 tile, BK=64, 512 threads / 8 waves (4M x 2N), wave tile 64x64,
// A double-buffered in 64 KB LDS, B global->register. 512 blocks -> 2 blocks
// per CU (16 waves): independent blocks overlap each other's LDS/DMA/MFMA and
// absorb the epilogue HBM-write tail.
__global__ __launch_bounds__(512, 4) void gemm_cos_kernel(const unsigned short* __restrict__ Xb,
                                                          const unsigned short* __restrict__ Yb,
                                                          const float* __restrict__ rnx,
                                                          const float* __restrict__ rny,
                                                          float* __restrict__ out) {
    __shared__ __bf16 As[2 * ABUF_E];  // 64 KB

    const int tid = threadIdx.x;

    // XCD-aware bijective swizzle: nwg = 32*16 = 512, 512 % 8 == 0.
    const int lin = (int)(blockIdx.y * gridDim.x + blockIdx.x);
    const int swz = (lin & 7) * 64 + (lin >> 3);
    const int bm = swz >> 5;   // 0..15
    const int bn = swz & 31;   // 0..31

    // A staging: thread t covers seg-row (t>>3) (0..63), chunk slot (t&7);
    // fetches global chunk (t&7)^(srow&7) so LDS slot c' holds chunk c'^(row&7).
    const int srow = tid >> 3;
    const int gch = (tid & 7) ^ (srow & 7);
    const unsigned short* gAsrc = Xb + (size_t)(bm * BM + srow) * KDIM + gch * 8;

    const int lane = tid & 63;
    const int wv = tid >> 6;
    const int wm = wv >> 1;   // 0..3 -> A rows wm*64..
    const int wn = wv & 1;    // 0..1 -> B cols wn*64..
    const int n32 = lane & 31;
    const int half = lane >> 5;
    const int rsw = n32 & 7;

    const int aB0 = (wm * 64 + n32) * BK;
    const int aB1 = (wm * 64 + 32 + n32) * BK;

    // B global row bases for the wave's two 32-col groups.
    const unsigned short* gB0 = Yb + (size_t)(bn * BN + wn * 64 + n32) * KDIM;
    const unsigned short* gB1 = Yb + (size_t)(bn * BN + wn * 64 + 32 + n32) * KDIM;

    f32x16 acc00 = {}, acc01 = {}, acc10 = {}, acc11 = {};

    __bf16* buf0 = As;
    __bf16* buf1 = As + ABUF_E;

    // ---- prologue: stage A tile 0 -> buf0
#pragma unroll
    for (int seg = 0; seg < 4; ++seg)
        async_copy16(gAsrc + (size_t)(seg * 64) * KDIM, buf0 + seg * 4096 + tid * 8);
    __syncthreads();

    // ---- main loop: ping-pong pairs, staging t+1 during t
#pragma unroll 1
    for (int t = 0; t < NT - 2; t += 2) {
        ktile<true>(buf0, buf1, gAsrc, (t + 1) * BK, gB0, gB1, t * BK,
                    aB0, aB1, half, rsw, tid, acc00, acc01, acc10, acc11);
        ktile<true>(buf1, buf0, gAsrc, (t + 2) * BK, gB0, gB1, (t + 1) * BK,
                    aB0, aB1, half, rsw, tid, acc00, acc01, acc10, acc11);
    }
    // tile 14 (buf0): stage tile 15 -> buf1
    ktile<true>(buf0, buf1, gAsrc, 15 * BK, gB0, gB1, 14 * BK,
                aB0, aB1, half, rsw, tid, acc00, acc01, acc10, acc11);
    // tile 15 (buf1): no staging
    ktile<false>(buf1, buf0, gAsrc, 0, gB0, gB1, 15 * BK,
                 aB0, aB1, half, rsw, tid, acc00, acc01, acc10, acc11);

    // C/D layout (measured m74/m101): col = lane&31, row = (reg&3) + 8*(reg>>2) + 4*(lane>>5).
    const int grb = bm * BM + wm * 64 + 4 * half;
    const int gcb = bn * BN + wn * 64 + n32;
    const float sy0 = rny[gcb] * TEMP_INV;
    const float sy1 = rny[gcb + 32] * TEMP_INV;

#pragma unroll
    for (int r = 0; r < 16; ++r) {
        const int ro = (r & 3) + 8 * (r >> 2);
        {
            const int grow = grb + ro;
            const float rx = rnx[grow];
            out[(size_t)grow * NDIM + gcb] = acc00[r] * rx * sy0;
            out[(size_t)grow * NDIM + gcb + 32] = acc01[r] * rx * sy1;
        }
        {
            const int grow = grb + 32 + ro;
            const float rx = rnx[grow];
            out[(size_t)grow * NDIM + gcb] = acc10[r] * rx * sy0;
            out[(size_t)grow * NDIM + gcb + 32] = acc11[r] * rx * sy1;
        }
    }
}

extern "C" void kernel_launch(void* const* d_in, const int* in_sizes, int n_in,
                              void* d_out, int out_size, void* d_ws, size_t ws_size,
                              hipStream_t stream) {
    const float* x = (const float*)d_in[0];
    const float* y = (const float*)d_in[1];
    float* out = (float*)d_out;

    char* ws = (char*)d_ws;
    unsigned short* Xb = (unsigned short*)ws;                              // 8 MB
    unsigned short* Yb = (unsigned short*)(ws + (size_t)MDIM * KDIM * 2);  // 8 MB
    float* rnx = (float*)(ws + (size_t)(MDIM + NDIM) * KDIM * 2);
    float* rny = rnx + MDIM;

    prep_kernel<<<dim3(MDIM / 4, 2), 256, 0, stream>>>(x, y, Xb, Yb, rnx, rny);
    gemm_cos_kernel<<<dim3(NDIM / BN, MDIM / BM), 512, 0, stream>>>(Xb, Yb, rnx, rny, out);
}